// Round 16
// baseline (694.089 us; speedup 1.0000x reference)
//
#include <hip/hip_runtime.h>

#define D 128
#define RMAX 16

typedef short s16x8 __attribute__((ext_vector_type(8)));
typedef float f32x4 __attribute__((ext_vector_type(4)));

__device__ inline unsigned short f2b(float f) {
    unsigned u = __builtin_bit_cast(unsigned, f);
    unsigned r = (u + 0x7FFFu + ((u >> 16) & 1u)) >> 16;
    return (unsigned short)r;
}
__device__ inline float b2f(unsigned short h) {
    unsigned u = ((unsigned)h) << 16;
    return __builtin_bit_cast(float, u);
}

// ---------------- histogram: deg[r*N+dst] ----------------

__global__ void k_count2(const int* __restrict__ etype, const int* __restrict__ dstA,
                         int E, int N, int* __restrict__ deg) {
    int e = blockIdx.x * blockDim.x + threadIdx.x;
    if (e < E) atomicAdd(&deg[etype[e] * N + dstA[e]], 1);
}

// padded relation offsets from degOff (after scan), plus trailing self pseudo-relation
__global__ void k_offsets(const int* __restrict__ degOff, int* __restrict__ po,
                          int R, int N, int E) {
    if (threadIdx.x == 0 && blockIdx.x == 0) {
        int acc = 0;
        for (int r = 0; r < R; ++r) {
            int hi = (r + 1 < R) ? degOff[(size_t)(r + 1) * N] : E;
            int c = hi - degOff[(size_t)r * N];
            po[r] = acc;
            acc += ((c + 127) / 128) * 128;
        }
        po[R] = acc;
        acc += ((N + 127) / 128) * 128;
        po[R + 1] = acc;
    }
}

// ---------------- generic scans (exclusive, over R*N) ----------------

template<int VPT>
__global__ void k_scan_blk(const int* __restrict__ in, int* __restrict__ tmp,
                           int* __restrict__ bsum, int n) {
    __shared__ int sd[256];
    int t = threadIdx.x;
    long base = (long)blockIdx.x * (256 * VPT) + (long)t * VPT;
    int s[VPT];
    int tsum = 0;
    #pragma unroll
    for (int k = 0; k < VPT; ++k) { s[k] = (base + k < n) ? in[base + k] : 0; tsum += s[k]; }
    sd[t] = tsum;
    __syncthreads();
    for (int off = 1; off < 256; off <<= 1) {
        int v = (t >= off) ? sd[t - off] : 0;
        __syncthreads();
        sd[t] += v;
        __syncthreads();
    }
    int run = sd[t] - tsum;
    #pragma unroll
    for (int k = 0; k < VPT; ++k) { if (base + k < n) tmp[base + k] = run; run += s[k]; }
    if (t == 255) bsum[blockIdx.x] = sd[255];
}

__global__ void k_scan2(const int* __restrict__ bsum, int* __restrict__ boff, int nb) {
    __shared__ int sd[256];
    int t = threadIdx.x;
    int v = (t < nb) ? bsum[t] : 0;
    sd[t] = v;
    __syncthreads();
    for (int off = 1; off < 256; off <<= 1) {
        int w = (t >= off) ? sd[t - off] : 0;
        __syncthreads();
        sd[t] += w;
        __syncthreads();
    }
    if (t < nb) boff[t] = sd[t] - v;
}

__global__ void k_scan3(const int* __restrict__ tmp, const int* __restrict__ boff,
                        int* __restrict__ out, int n, int shift) {
    int i = blockIdx.x * 256 + threadIdx.x;
    if (i < n) out[i] = tmp[i] + boff[i >> shift];
}

// ---------------- scatter: slotSrc in (relation, dst)-sorted order ----------------

__global__ void k_scatter3(const int* __restrict__ etype, const int* __restrict__ srcA,
                           const int* __restrict__ dstA, int E, int N, int R,
                           const int* __restrict__ degOff, const int* __restrict__ po,
                           int* __restrict__ binCur, int* __restrict__ slotSrc) {
    int t = blockIdx.x * 256 + threadIdx.x;
    if (t < E) {
        int r = etype[t];
        int bin = r * N + dstA[t];
        int rank = atomicAdd(&binCur[bin], 1);
        int pos = po[r] + (degOff[bin] - degOff[r * N]) + rank;
        slotSrc[pos] = srcA[t];
    } else if (t < E + N) {
        int n = t - E;
        slotSrc[po[R] + n] = n;
    }
}

// ---------------- fused prep: emb->bf16, weights -> bf16 k-minor PRE-SWIZZLED ----------------

__global__ void k_prep(const float* __restrict__ emb,
                       const float* __restrict__ rw1, const float* __restrict__ sl1,
                       const float* __restrict__ rw2, const float* __restrict__ sl2,
                       const float* __restrict__ pw1,
                       unsigned short* __restrict__ embb,
                       unsigned short* __restrict__ wAll1,
                       unsigned short* __restrict__ wAll2,
                       unsigned short* __restrict__ pw1T,
                       int N, int R)
{
    long t = (long)blockIdx.x * 256 + threadIdx.x;
    long u0 = (long)N * D / 4;
    if (t < u0) {
        long i = t * 4;
        f32x4 v = *(const f32x4*)(emb + i);
        unsigned a0 = (unsigned)f2b(v[0]) | ((unsigned)f2b(v[1]) << 16);
        unsigned a1 = (unsigned)f2b(v[2]) | ((unsigned)f2b(v[3]) << 16);
        uint2 o; o.x = a0; o.y = a1;
        *(uint2*)(embb + i) = o;
        return;
    }
    t -= u0;
    long uW = (long)(R + 1) * D * D;
    if (t < 2 * uW) {
        const float* rw = (t < uW) ? rw1 : rw2;
        const float* sl = (t < uW) ? sl1 : sl2;
        unsigned short* o = (t < uW) ? wAll1 : wAll2;
        long u = (t < uW) ? t : t - uW;
        int r = (int)(u >> 14);          // D*D = 16384
        int nb = (int)(u & 16383);
        int n = nb >> 7, kk = nb & 127;
        int ke = kk ^ ((n & 7) << 3);    // pre-swizzle within row
        float v = (r < R) ? rw[((size_t)r * D + ke) * D + n] : sl[(size_t)ke * D + n];
        o[u] = f2b(v);
        return;
    }
    t -= 2 * uW;
    if (t < 3 * D * D) {
        int n = (int)(t / 384), ck = (int)(t - n * 384);
        int ch = ck >> 7, kl = (ck & 127) ^ ((n & 7) << 3);
        pw1T[t] = f2b(pw1[(size_t)(ch * 128 + kl) * 128 + n]);
    }
}

// ---------------- phase A: per-edge UNSCALED messages via MFMA (streaming y-write) ----------------
// Half-staged B and C (16KB LDS); acc live-range halved -> <=64 VGPR, 8 waves/SIMD.

__global__ __launch_bounds__(256, 8) void k_gemm_msg(
    const unsigned short* __restrict__ xb,
    const unsigned short* __restrict__ wAll,    // pre-swizzled, (R+1) matrices
    const int* __restrict__ slotSrc,
    const int* __restrict__ po, int R,
    unsigned short* __restrict__ y)
{
    __shared__ unsigned char smB[16384];
    int tid = threadIdx.x;
    int row0 = blockIdx.x * 128;
    if (row0 >= po[R + 1]) return;
    int r = 0;
    while (row0 >= po[r + 1]) ++r;

    int lane = tid & 63, wid = tid >> 6;
    int lo = lane & 15, hi = lane >> 4;

    // ---- A preload: sequential slotSrc read, then one-level gather; issued first ----
    int r0g = wid * 32 + lo, r1g = r0g + 16;
    int sv0 = slotSrc[row0 + r0g];
    int sv1 = slotSrc[row0 + r1g];
    const unsigned short* xrow0 = xb + (size_t)sv0 * D;
    const unsigned short* xrow1 = xb + (size_t)sv1 * D;
    s16x8 a0[4], a1[4];
    #pragma unroll
    for (int ks = 0; ks < 4; ++ks) {
        a0[ks] = *(const s16x8*)(xrow0 + ks * 32 + hi * 8);
        a1[ks] = *(const s16x8*)(xrow1 + ks * 32 + hi * 8);
    }

    const int4* wsrc = (const int4*)(wAll + (size_t)r * D * D);

    #pragma unroll
    for (int h = 0; h < 2; ++h) {
        if (h) __syncthreads();           // C(h-1) reads of smB complete
        {   // stage B half h (16KB, pre-swizzled rows for out-cols h*64..)
            int4* dstl = (int4*)smB;
            #pragma unroll
            for (int i = 0; i < 4; ++i)
                dstl[tid + i * 256] = wsrc[h * 1024 + tid + i * 256];
        }
        __syncthreads();

        f32x4 acc[2][4];
        #pragma unroll
        for (int q = 0; q < 2; ++q)
            #pragma unroll
            for (int n2 = 0; n2 < 4; ++n2) acc[q][n2] = (f32x4){0, 0, 0, 0};

        #pragma unroll
        for (int ks = 0; ks < 4; ++ks) {
            int kb = ks * 64 + hi * 16;
            #pragma unroll
            for (int n2 = 0; n2 < 4; ++n2) {
                int cloc = n2 * 16 + lo;
                s16x8 bf = *(const s16x8*)(smB + cloc * 256 + (kb ^ ((cloc & 7) << 4)));
                acc[0][n2] = __builtin_amdgcn_mfma_f32_16x16x32_bf16(a0[ks], bf, acc[0][n2], 0, 0, 0);
                acc[1][n2] = __builtin_amdgcn_mfma_f32_16x16x32_bf16(a1[ks], bf, acc[1][n2], 0, 0, 0);
            }
        }
        __syncthreads();                  // B reads done before C staging overwrites

        // ---- stage C half h (128 rows x 128B) ----
        #pragma unroll
        for (int g = 0; g < 2; ++g) {
            #pragma unroll
            for (int reg = 0; reg < 4; ++reg) {
                int rl = wid * 32 + g * 16 + hi * 4 + reg;
                #pragma unroll
                for (int n2 = 0; n2 < 4; ++n2) {
                    int byteoff = rl * 128 + (((n2 * 32 + (lo >> 3) * 16) ^ ((rl & 7) << 4)) + (lo & 7) * 2);
                    *(unsigned short*)(smB + byteoff) = f2b(acc[g][n2][reg]);
                }
            }
        }
        __syncthreads();
        {   // write C half h (streaming, slot order)
            int m = tid >> 1, half2 = tid & 1;
            unsigned short* dst = y + (size_t)(row0 + m) * D + h * 64 + half2 * 32;
            #pragma unroll
            for (int i = 0; i < 4; ++i) {
                int c = half2 * 4 + i;
                int4 v = *(const int4*)(smB + m * 128 + ((c * 16) ^ ((m & 7) << 4)));
                *(int4*)(dst + i * 8) = v;
            }
        }
    }
}

// ---------------- phase B: 9-stream segmented sum (runs contiguous per relation) ----------------

template<bool RELU>
__global__ void k_reduce2(const unsigned short* __restrict__ y,
                          const int* __restrict__ degOff,
                          const int* __restrict__ po,
                          const float* __restrict__ bias,
                          unsigned short* __restrict__ out, int N, int R, int E)
{
    __shared__ int rbase[RMAX + 1];
    int tid = threadIdx.x;
    if (tid <= R) rbase[tid] = (tid < R) ? (po[tid] - degOff[(size_t)tid * N]) : po[R];
    __syncthreads();

    int team = tid >> 4, cj = tid & 15;   // 16 lanes cover one 256B row
    float b[8];
    *(f32x4*)(b)     = *(const f32x4*)(bias + cj * 8);
    *(f32x4*)(b + 4) = *(const f32x4*)(bias + cj * 8 + 4);
    int dbase = blockIdx.x * 64 + team * 4;
    for (int i = 0; i < 4; ++i) {
        int d = dbase + i;
        if (d >= N) return;
        float a[8];
        {   // self message (scale 1)
            int4 v = *(const int4*)(y + (size_t)(rbase[R] + d) * D + cj * 8);
            const unsigned short* hp = (const unsigned short*)&v;
            #pragma unroll
            for (int j = 0; j < 8; ++j) a[j] = b[j] + b2f(hp[j]);
        }
        for (int r = 0; r < R; ++r) {
            int bin = r * N + d;
            int o0 = degOff[bin];
            int o1 = (bin + 1 < R * N) ? degOff[bin + 1] : E;
            int len = o1 - o0;
            if (!len) continue;
            long start = rbase[r] + o0;
            float s8[8];
            #pragma unroll
            for (int j = 0; j < 8; ++j) s8[j] = 0.0f;
            for (int q = 0; q < len; ++q) {
                int4 v = *(const int4*)(y + (size_t)(start + q) * D + cj * 8);
                const unsigned short* hp = (const unsigned short*)&v;
                #pragma unroll
                for (int j = 0; j < 8; ++j) s8[j] += b2f(hp[j]);
            }
            float inv = 1.0f / (float)len;
            #pragma unroll
            for (int j = 0; j < 8; ++j) a[j] = fmaf(s8[j], inv, a[j]);
        }
        unsigned short o[8];
        #pragma unroll
        for (int j = 0; j < 8; ++j) {
            float v = RELU ? fmaxf(a[j], 0.0f) : a[j];
            o[j] = f2b(v);
        }
        *(int4*)(out + (size_t)d * D + cj * 8) = *(const int4*)o;
    }
}

// ---------------- pair scoring ----------------

__global__ __launch_bounds__(256) void k_score(
    const unsigned short* __restrict__ x2b,
    const int* __restrict__ drug, const int* __restrict__ dis,
    const unsigned short* __restrict__ pw1T,  // pre-swizzled [128][384]
    const float* __restrict__ pb1, const float* __restrict__ pw2,
    const float* __restrict__ pb2, float* __restrict__ outp, int P)
{
    __shared__ unsigned char smA[32768];
    __shared__ unsigned char smB[32768];
    __shared__ float pb1s[128];
    __shared__ float pw2s[128];
    int tid = threadIdx.x;
    long p0 = (long)blockIdx.x * 128;
    if (tid < 128) { pb1s[tid] = pb1[tid]; pw2s[tid] = pw2[tid]; }
    float pb2v = pb2[0];

    int lane = tid & 63, wid = tid >> 6;
    int lo = lane & 15, hi = lane >> 4;
    f32x4 acc[2][8];
    #pragma unroll
    for (int q = 0; q < 2; ++q)
        #pragma unroll
        for (int b = 0; b < 8; ++b) acc[q][b] = (f32x4){0, 0, 0, 0};

    for (int chn = 0; chn < 3; ++chn) {
        {   // stage B chunk: linear (content pre-swizzled)
            const int4* src = (const int4*)pw1T;
            int4* dstl = (int4*)smB;
            #pragma unroll
            for (int i = 0; i < 8; ++i) {
                int q = tid + i * 256;
                int n = q >> 4, c = q & 15;
                dstl[q] = src[n * 48 + chn * 16 + c];
            }
        }
        {   // stage A chunk (swizzled on write + read)
            int m = tid >> 1, half = tid & 1;
            long p = p0 + m;
            int4 z = {0, 0, 0, 0};
            if (p < P) {
                const int4* da = (const int4*)(x2b + (size_t)drug[p] * D);
                const int4* db = (const int4*)(x2b + (size_t)dis[p] * D);
                for (int c = half * 8; c < half * 8 + 8; ++c) {
                    int4 v;
                    if (chn == 0) v = da[c];
                    else if (chn == 1) v = db[c];
                    else {
                        int4 va = da[c], vb = db[c];
                        const unsigned short* ap = (const unsigned short*)&va;
                        const unsigned short* bp = (const unsigned short*)&vb;
                        unsigned short o[8];
                        #pragma unroll
                        for (int j = 0; j < 8; ++j) o[j] = f2b(b2f(ap[j]) * b2f(bp[j]));
                        v = *(const int4*)o;
                    }
                    *(int4*)(smA + m * 256 + ((c * 16) ^ ((m & 7) << 4))) = v;
                }
            } else {
                for (int c = half * 8; c < half * 8 + 8; ++c)
                    *(int4*)(smA + m * 256 + ((c * 16) ^ ((m & 7) << 4))) = z;
            }
        }
        __syncthreads();

        #pragma unroll
        for (int ks = 0; ks < 4; ++ks) {
            int kb = ks * 64 + hi * 16;
            int r0 = wid * 32 + lo, r1 = r0 + 16;
            s16x8 a0 = *(const s16x8*)(smA + r0 * 256 + (kb ^ ((r0 & 7) << 4)));
            s16x8 a1 = *(const s16x8*)(smA + r1 * 256 + (kb ^ ((r1 & 7) << 4)));
            #pragma unroll
            for (int n = 0; n < 8; ++n) {
                int cr = n * 16 + lo;
                s16x8 bf = *(const s16x8*)(smB + cr * 256 + (kb ^ ((cr & 7) << 4)));
                acc[0][n] = __builtin_amdgcn_mfma_f32_16x16x32_bf16(a0, bf, acc[0][n], 0, 0, 0);
                acc[1][n] = __builtin_amdgcn_mfma_f32_16x16x32_bf16(a1, bf, acc[1][n], 0, 0, 0);
            }
        }
        __syncthreads();
    }

    #pragma unroll
    for (int m2 = 0; m2 < 2; ++m2)
        #pragma unroll
        for (int reg = 0; reg < 4; ++reg) {
            float s = 0.0f;
            #pragma unroll
            for (int n = 0; n < 8; ++n) {
                int col = n * 16 + lo;
                float v = acc[m2][n][reg] + pb1s[col];
                v = fmaxf(v, 0.0f);
                s = fmaf(v, pw2s[col], s);
            }
            s += __shfl_xor(s, 1, 64);
            s += __shfl_xor(s, 2, 64);
            s += __shfl_xor(s, 4, 64);
            s += __shfl_xor(s, 8, 64);
            long p = p0 + wid * 32 + m2 * 16 + hi * 4 + reg;
            if (lo == 0 && p < P) outp[p] = s + pb2v;
        }
}

// ---------------- launch ----------------

extern "C" void kernel_launch(void* const* d_in, const int* in_sizes, int n_in,
                              void* d_out, int out_size, void* d_ws, size_t ws_size,
                              hipStream_t stream) {
    const int*   edge_index = (const int*)d_in[0];
    const int*   edge_type  = (const int*)d_in[1];
    const int*   drug       = (const int*)d_in[2];
    const int*   dis        = (const int*)d_in[3];
    const float* emb        = (const float*)d_in[4];
    const float* rw1        = (const float*)d_in[5];
    const float* sl1        = (const float*)d_in[6];
    const float* b1         = (const float*)d_in[7];
    const float* rw2        = (const float*)d_in[8];
    const float* sl2        = (const float*)d_in[9];
    const float* b2         = (const float*)d_in[10];
    const float* pw1        = (const float*)d_in[11];
    const float* pb1        = (const float*)d_in[12];
    const float* pw2        = (const float*)d_in[13];
    const float* pb2        = (const float*)d_in[14];

    const int E = in_sizes[1];
    const int P = in_sizes[2];
    const int N = in_sizes[4] / D;
    const int R = in_sizes[5] / (D * D);

    const int* srcA = edge_index;
    const int* dstA = edge_index + E;

    const int slotN = E + N + 128 * (R + 2);

    char* ws = (char*)d_ws;
    unsigned short* embb = (unsigned short*)ws; ws += (size_t)N * D * 2;   // aliased as x2b
    unsigned short* x1b  = (unsigned short*)ws; ws += (size_t)N * D * 2;
    unsigned short* y    = (unsigned short*)ws; ws += (size_t)slotN * D * 2;
    unsigned short* wAll1 = (unsigned short*)ws; ws += (size_t)(R + 1) * D * D * 2;
    unsigned short* wAll2 = (unsigned short*)ws; ws += (size_t)(R + 1) * D * D * 2;
    unsigned short* pw1T  = (unsigned short*)ws; ws += (size_t)3 * D * D * 2;
    // zero region (single memset): deg | binCur | slotSrc
    int*   deg     = (int*)ws;   ws += (size_t)R * N * 4;
    int*   binCur  = (int*)ws;   ws += (size_t)R * N * 4;
    int*   slotSrc = (int*)ws;   ws += (size_t)slotN * 4;
    size_t zbytes = (size_t)(2 * R * N + slotN) * 4;
    int* degOff  = (int*)ws; ws += (size_t)R * N * 4;
    int* bsum    = (int*)ws; ws += 256 * 4;
    int* boff    = (int*)ws; ws += 256 * 4;
    int* po      = (int*)ws; ws += 256;
    unsigned short* x2b = embb;

    hipMemsetAsync(deg, 0, zbytes, stream);

    // fused prep (emb->bf16, weights bf16 k-minor pre-swizzled)
    long u0 = (long)N * D / 4;
    long uW = (long)(R + 1) * D * D;
    long utot = u0 + 2 * uW + 3 * D * D;
    k_prep<<<(int)((utot + 255) / 256), 256, 0, stream>>>(emb, rw1, sl1, rw2, sl2, pw1,
                                                          embb, wAll1, wAll2, pw1T, N, R);

    k_count2<<<(E + 255) / 256, 256, 0, stream>>>(edge_type, dstA, E, N, deg);

    // exclusive scan of deg over R*N -> degOff
    int nbS = (R * N + 4095) / 4096;
    k_scan_blk<16><<<nbS, 256, 0, stream>>>(deg, degOff, bsum, R * N);
    k_scan2<<<1, 256, 0, stream>>>(bsum, boff, nbS);
    k_scan3<<<(R * N + 255) / 256, 256, 0, stream>>>(degOff, boff, degOff, R * N, 12);

    k_offsets<<<1, 1, 0, stream>>>(degOff, po, R, N, E);

    // fill slotSrc in (relation,dst)-sorted order (+ self rows)
    k_scatter3<<<(E + N + 255) / 256, 256, 0, stream>>>(edge_type, srcA, dstA, E, N, R,
                                                        degOff, po, binCur, slotSrc);

    int gridM = (E + 127) / 128 + (N + 127) / 128 + R + 2;
    int gridR = (N + 63) / 64;

    // layer 1
    k_gemm_msg<<<gridM, 256, 0, stream>>>(embb, wAll1, slotSrc, po, R, y);
    k_reduce2<true><<<gridR, 256, 0, stream>>>(y, degOff, po, b1, x1b, N, R, E);
    // layer 2
    k_gemm_msg<<<gridM, 256, 0, stream>>>(x1b, wAll2, slotSrc, po, R, y);
    k_reduce2<false><<<gridR, 256, 0, stream>>>(y, degOff, po, b2, x2b, N, R, E);
    // scoring
    k_score<<<(P + 127) / 128, 256, 0, stream>>>(x2b, drug, dis, pw1T, pb1, pw2, pb2,
                                                 (float*)d_out, P);
}

// Round 17
// 470.556 us; speedup vs baseline: 1.4750x; 1.4750x over previous
//
#include <hip/hip_runtime.h>

#define D 128
#define RMAX 16

typedef short s16x8 __attribute__((ext_vector_type(8)));
typedef float f32x4 __attribute__((ext_vector_type(4)));

__device__ inline unsigned short f2b(float f) {
    unsigned u = __builtin_bit_cast(unsigned, f);
    unsigned r = (u + 0x7FFFu + ((u >> 16) & 1u)) >> 16;
    return (unsigned short)r;
}
__device__ inline float b2f(unsigned short h) {
    unsigned u = ((unsigned)h) << 16;
    return __builtin_bit_cast(float, u);
}

// ---------------- histogram: deg[r*N+dst] ----------------

__global__ void k_count2(const int* __restrict__ etype, const int* __restrict__ dstA,
                         int E, int N, int* __restrict__ deg) {
    int e = blockIdx.x * blockDim.x + threadIdx.x;
    if (e < E) atomicAdd(&deg[etype[e] * N + dstA[e]], 1);
}

// padded relation offsets from degOff (after scan): 512-slot tiles per segment
__global__ void k_offsets(const int* __restrict__ degOff, int* __restrict__ po,
                          int R, int N, int E) {
    if (threadIdx.x == 0 && blockIdx.x == 0) {
        int acc = 0;
        for (int r = 0; r < R; ++r) {
            int hi = (r + 1 < R) ? degOff[(size_t)(r + 1) * N] : E;
            int c = hi - degOff[(size_t)r * N];
            po[r] = acc;
            acc += ((c + 511) / 512) * 512;
        }
        po[R] = acc;
        acc += ((N + 511) / 512) * 512;
        po[R + 1] = acc;
    }
}

// ---------------- generic scans (exclusive, over R*N) ----------------

template<int VPT>
__global__ void k_scan_blk(const int* __restrict__ in, int* __restrict__ tmp,
                           int* __restrict__ bsum, int n) {
    __shared__ int sd[256];
    int t = threadIdx.x;
    long base = (long)blockIdx.x * (256 * VPT) + (long)t * VPT;
    int s[VPT];
    int tsum = 0;
    #pragma unroll
    for (int k = 0; k < VPT; ++k) { s[k] = (base + k < n) ? in[base + k] : 0; tsum += s[k]; }
    sd[t] = tsum;
    __syncthreads();
    for (int off = 1; off < 256; off <<= 1) {
        int v = (t >= off) ? sd[t - off] : 0;
        __syncthreads();
        sd[t] += v;
        __syncthreads();
    }
    int run = sd[t] - tsum;
    #pragma unroll
    for (int k = 0; k < VPT; ++k) { if (base + k < n) tmp[base + k] = run; run += s[k]; }
    if (t == 255) bsum[blockIdx.x] = sd[255];
}

__global__ void k_scan2(const int* __restrict__ bsum, int* __restrict__ boff, int nb) {
    __shared__ int sd[256];
    int t = threadIdx.x;
    int v = (t < nb) ? bsum[t] : 0;
    sd[t] = v;
    __syncthreads();
    for (int off = 1; off < 256; off <<= 1) {
        int w = (t >= off) ? sd[t - off] : 0;
        __syncthreads();
        sd[t] += w;
        __syncthreads();
    }
    if (t < nb) boff[t] = sd[t] - v;
}

__global__ void k_scan3(const int* __restrict__ tmp, const int* __restrict__ boff,
                        int* __restrict__ out, int n, int shift) {
    int i = blockIdx.x * 256 + threadIdx.x;
    if (i < n) out[i] = tmp[i] + boff[i >> shift];
}

// ---------------- scatter: slotSrc in (relation, dst)-sorted order ----------------

__global__ void k_scatter3(const int* __restrict__ etype, const int* __restrict__ srcA,
                           const int* __restrict__ dstA, int E, int N, int R,
                           const int* __restrict__ degOff, const int* __restrict__ po,
                           int* __restrict__ binCur, int* __restrict__ slotSrc) {
    int t = blockIdx.x * 256 + threadIdx.x;
    if (t < E) {
        int r = etype[t];
        int bin = r * N + dstA[t];
        int rank = atomicAdd(&binCur[bin], 1);
        int pos = po[r] + (degOff[bin] - degOff[r * N]) + rank;
        slotSrc[pos] = srcA[t];
    } else if (t < E + N) {
        int n = t - E;
        slotSrc[po[R] + n] = n;
    }
}

// ---------------- fused prep: emb->bf16, weights -> bf16 k-minor PRE-SWIZZLED ----------------

__global__ void k_prep(const float* __restrict__ emb,
                       const float* __restrict__ rw1, const float* __restrict__ sl1,
                       const float* __restrict__ rw2, const float* __restrict__ sl2,
                       const float* __restrict__ pw1,
                       unsigned short* __restrict__ embb,
                       unsigned short* __restrict__ wAll1,
                       unsigned short* __restrict__ wAll2,
                       unsigned short* __restrict__ pw1T,
                       int N, int R)
{
    long t = (long)blockIdx.x * 256 + threadIdx.x;
    long u0 = (long)N * D / 4;
    if (t < u0) {
        long i = t * 4;
        f32x4 v = *(const f32x4*)(emb + i);
        unsigned a0 = (unsigned)f2b(v[0]) | ((unsigned)f2b(v[1]) << 16);
        unsigned a1 = (unsigned)f2b(v[2]) | ((unsigned)f2b(v[3]) << 16);
        uint2 o; o.x = a0; o.y = a1;
        *(uint2*)(embb + i) = o;
        return;
    }
    t -= u0;
    long uW = (long)(R + 1) * D * D;
    if (t < 2 * uW) {
        const float* rw = (t < uW) ? rw1 : rw2;
        const float* sl = (t < uW) ? sl1 : sl2;
        unsigned short* o = (t < uW) ? wAll1 : wAll2;
        long u = (t < uW) ? t : t - uW;
        int r = (int)(u >> 14);          // D*D = 16384
        int nb = (int)(u & 16383);
        int n = nb >> 7, kk = nb & 127;
        int ke = kk ^ ((n & 7) << 3);    // pre-swizzle within row
        float v = (r < R) ? rw[((size_t)r * D + ke) * D + n] : sl[(size_t)ke * D + n];
        o[u] = f2b(v);
        return;
    }
    t -= 2 * uW;
    if (t < 3 * D * D) {
        int n = (int)(t / 384), ck = (int)(t - n * 384);
        int ch = ck >> 7, kl = (ck & 127) ^ ((n & 7) << 3);
        pw1T[t] = f2b(pw1[(size_t)(ch * 128 + kl) * 128 + n]);
    }
}

// ---------------- phase A: per-edge UNSCALED messages via MFMA (streaming y-write) ----------------
// 512-slot blocks (4 x 128-row tiles, single relation), r15 body per tile.

__global__ __launch_bounds__(256) void k_gemm_msg(
    const unsigned short* __restrict__ xb,
    const unsigned short* __restrict__ wAll,    // pre-swizzled, (R+1) matrices
    const int* __restrict__ slotSrc,
    const int* __restrict__ po, int R,
    unsigned short* __restrict__ y)
{
    __shared__ unsigned char smB[16384];
    int tid = threadIdx.x;
    int base0 = blockIdx.x * 512;
    if (base0 >= po[R + 1]) return;
    int r = 0;
    while (base0 >= po[r + 1]) ++r;

    int lane = tid & 63, wid = tid >> 6;
    int lo = lane & 15, hi = lane >> 4;
    const int4* wsrc = (const int4*)(wAll + (size_t)r * D * D);

    for (int t = 0; t < 4; ++t) {
        int row0 = base0 + t * 128;

        // ---- A preload: sequential slotSrc read, then one-level gather; issued first ----
        int r0g = wid * 32 + lo, r1g = r0g + 16;
        int sv0 = slotSrc[row0 + r0g];
        int sv1 = slotSrc[row0 + r1g];
        const unsigned short* xrow0 = xb + (size_t)sv0 * D;
        const unsigned short* xrow1 = xb + (size_t)sv1 * D;
        s16x8 a0[4], a1[4];
        #pragma unroll
        for (int ks = 0; ks < 4; ++ks) {
            a0[ks] = *(const s16x8*)(xrow0 + ks * 32 + hi * 8);
            a1[ks] = *(const s16x8*)(xrow1 + ks * 32 + hi * 8);
        }

        f32x4 acc[2][8];
        #pragma unroll
        for (int q = 0; q < 2; ++q)
            #pragma unroll
            for (int n = 0; n < 8; ++n) acc[q][n] = (f32x4){0, 0, 0, 0};

        // ---- B halves: stage 16KB, MFMA 4 outcol-groups each ----
        #pragma unroll
        for (int h = 0; h < 2; ++h) {
            if (h | t) __syncthreads();   // prior smB reads (mfma or C-write) complete
            {
                int4* dstl = (int4*)smB;
                #pragma unroll
                for (int i = 0; i < 4; ++i)
                    dstl[tid + i * 256] = wsrc[h * 1024 + tid + i * 256];
            }
            __syncthreads();
            #pragma unroll
            for (int ks = 0; ks < 4; ++ks) {
                int kb = ks * 64 + hi * 16;
                #pragma unroll
                for (int n2 = 0; n2 < 4; ++n2) {
                    int cloc = n2 * 16 + lo;
                    s16x8 bf = *(const s16x8*)(smB + cloc * 256 + (kb ^ ((cloc & 7) << 4)));
                    acc[0][h * 4 + n2] = __builtin_amdgcn_mfma_f32_16x16x32_bf16(a0[ks], bf, acc[0][h * 4 + n2], 0, 0, 0);
                    acc[1][h * 4 + n2] = __builtin_amdgcn_mfma_f32_16x16x32_bf16(a1[ks], bf, acc[1][h * 4 + n2], 0, 0, 0);
                }
            }
        }

        // ---- C halves: bf16 stage 16KB (128 rows x 128B), streaming write ----
        #pragma unroll
        for (int h = 0; h < 2; ++h) {
            __syncthreads();              // previous smB reads complete
            #pragma unroll
            for (int g = 0; g < 2; ++g) {
                #pragma unroll
                for (int reg = 0; reg < 4; ++reg) {
                    int rl = wid * 32 + g * 16 + hi * 4 + reg;
                    #pragma unroll
                    for (int n2 = 0; n2 < 4; ++n2) {
                        int byteoff = rl * 128 + (((n2 * 32 + (lo >> 3) * 16) ^ ((rl & 7) << 4)) + (lo & 7) * 2);
                        *(unsigned short*)(smB + byteoff) = f2b(acc[g][h * 4 + n2][reg]);
                    }
                }
            }
            __syncthreads();
            {
                int m = tid >> 1, half2 = tid & 1;
                unsigned short* dst = y + (size_t)(row0 + m) * D + h * 64 + half2 * 32;
                #pragma unroll
                for (int i = 0; i < 4; ++i) {
                    int c = half2 * 4 + i;
                    int4 v = *(const int4*)(smB + m * 128 + ((c * 16) ^ ((m & 7) << 4)));
                    *(int4*)(dst + i * 8) = v;
                }
            }
        }
    }
}

// ---------------- phase B: 9-stream segmented sum (runs contiguous per relation) ----------------

template<bool RELU>
__global__ void k_reduce2(const unsigned short* __restrict__ y,
                          const int* __restrict__ degOff,
                          const int* __restrict__ po,
                          const float* __restrict__ bias,
                          unsigned short* __restrict__ out, int N, int R, int E)
{
    __shared__ int rbase[RMAX + 1];
    int tid = threadIdx.x;
    if (tid <= R) rbase[tid] = (tid < R) ? (po[tid] - degOff[(size_t)tid * N]) : po[R];
    __syncthreads();

    int team = tid >> 4, cj = tid & 15;   // 16 lanes cover one 256B row
    float b[8];
    *(f32x4*)(b)     = *(const f32x4*)(bias + cj * 8);
    *(f32x4*)(b + 4) = *(const f32x4*)(bias + cj * 8 + 4);
    int dbase = blockIdx.x * 64 + team * 4;
    for (int i = 0; i < 4; ++i) {
        int d = dbase + i;
        if (d >= N) return;
        float a[8];
        {   // self message (scale 1)
            int4 v = *(const int4*)(y + (size_t)(rbase[R] + d) * D + cj * 8);
            const unsigned short* hp = (const unsigned short*)&v;
            #pragma unroll
            for (int j = 0; j < 8; ++j) a[j] = b[j] + b2f(hp[j]);
        }
        for (int r = 0; r < R; ++r) {
            int bin = r * N + d;
            int o0 = degOff[bin];
            int o1 = (bin + 1 < R * N) ? degOff[bin + 1] : E;
            int len = o1 - o0;
            if (!len) continue;
            long start = rbase[r] + o0;
            float s8[8];
            #pragma unroll
            for (int j = 0; j < 8; ++j) s8[j] = 0.0f;
            for (int q = 0; q < len; ++q) {
                int4 v = *(const int4*)(y + (size_t)(start + q) * D + cj * 8);
                const unsigned short* hp = (const unsigned short*)&v;
                #pragma unroll
                for (int j = 0; j < 8; ++j) s8[j] += b2f(hp[j]);
            }
            float inv = 1.0f / (float)len;
            #pragma unroll
            for (int j = 0; j < 8; ++j) a[j] = fmaf(s8[j], inv, a[j]);
        }
        unsigned short o[8];
        #pragma unroll
        for (int j = 0; j < 8; ++j) {
            float v = RELU ? fmaxf(a[j], 0.0f) : a[j];
            o[j] = f2b(v);
        }
        *(int4*)(out + (size_t)d * D + cj * 8) = *(const int4*)o;
    }
}

// ---------------- pair scoring ----------------

__global__ __launch_bounds__(256) void k_score(
    const unsigned short* __restrict__ x2b,
    const int* __restrict__ drug, const int* __restrict__ dis,
    const unsigned short* __restrict__ pw1T,  // pre-swizzled [128][384]
    const float* __restrict__ pb1, const float* __restrict__ pw2,
    const float* __restrict__ pb2, float* __restrict__ outp, int P)
{
    __shared__ unsigned char smA[32768];
    __shared__ unsigned char smB[32768];
    __shared__ float pb1s[128];
    __shared__ float pw2s[128];
    int tid = threadIdx.x;
    long p0 = (long)blockIdx.x * 128;
    if (tid < 128) { pb1s[tid] = pb1[tid]; pw2s[tid] = pw2[tid]; }
    float pb2v = pb2[0];

    int lane = tid & 63, wid = tid >> 6;
    int lo = lane & 15, hi = lane >> 4;
    f32x4 acc[2][8];
    #pragma unroll
    for (int q = 0; q < 2; ++q)
        #pragma unroll
        for (int b = 0; b < 8; ++b) acc[q][b] = (f32x4){0, 0, 0, 0};

    for (int chn = 0; chn < 3; ++chn) {
        {   // stage B chunk: linear (content pre-swizzled)
            const int4* src = (const int4*)pw1T;
            int4* dstl = (int4*)smB;
            #pragma unroll
            for (int i = 0; i < 8; ++i) {
                int q = tid + i * 256;
                int n = q >> 4, c = q & 15;
                dstl[q] = src[n * 48 + chn * 16 + c];
            }
        }
        {   // stage A chunk (swizzled on write + read)
            int m = tid >> 1, half = tid & 1;
            long p = p0 + m;
            int4 z = {0, 0, 0, 0};
            if (p < P) {
                const int4* da = (const int4*)(x2b + (size_t)drug[p] * D);
                const int4* db = (const int4*)(x2b + (size_t)dis[p] * D);
                for (int c = half * 8; c < half * 8 + 8; ++c) {
                    int4 v;
                    if (chn == 0) v = da[c];
                    else if (chn == 1) v = db[c];
                    else {
                        int4 va = da[c], vb = db[c];
                        const unsigned short* ap = (const unsigned short*)&va;
                        const unsigned short* bp = (const unsigned short*)&vb;
                        unsigned short o[8];
                        #pragma unroll
                        for (int j = 0; j < 8; ++j) o[j] = f2b(b2f(ap[j]) * b2f(bp[j]));
                        v = *(const int4*)o;
                    }
                    *(int4*)(smA + m * 256 + ((c * 16) ^ ((m & 7) << 4))) = v;
                }
            } else {
                for (int c = half * 8; c < half * 8 + 8; ++c)
                    *(int4*)(smA + m * 256 + ((c * 16) ^ ((m & 7) << 4))) = z;
            }
        }
        __syncthreads();

        #pragma unroll
        for (int ks = 0; ks < 4; ++ks) {
            int kb = ks * 64 + hi * 16;
            int r0 = wid * 32 + lo, r1 = r0 + 16;
            s16x8 a0 = *(const s16x8*)(smA + r0 * 256 + (kb ^ ((r0 & 7) << 4)));
            s16x8 a1 = *(const s16x8*)(smA + r1 * 256 + (kb ^ ((r1 & 7) << 4)));
            #pragma unroll
            for (int n = 0; n < 8; ++n) {
                int cr = n * 16 + lo;
                s16x8 bf = *(const s16x8*)(smB + cr * 256 + (kb ^ ((cr & 7) << 4)));
                acc[0][n] = __builtin_amdgcn_mfma_f32_16x16x32_bf16(a0, bf, acc[0][n], 0, 0, 0);
                acc[1][n] = __builtin_amdgcn_mfma_f32_16x16x32_bf16(a1, bf, acc[1][n], 0, 0, 0);
            }
        }
        __syncthreads();
    }

    #pragma unroll
    for (int m2 = 0; m2 < 2; ++m2)
        #pragma unroll
        for (int reg = 0; reg < 4; ++reg) {
            float s = 0.0f;
            #pragma unroll
            for (int n = 0; n < 8; ++n) {
                int col = n * 16 + lo;
                float v = acc[m2][n][reg] + pb1s[col];
                v = fmaxf(v, 0.0f);
                s = fmaf(v, pw2s[col], s);
            }
            s += __shfl_xor(s, 1, 64);
            s += __shfl_xor(s, 2, 64);
            s += __shfl_xor(s, 4, 64);
            s += __shfl_xor(s, 8, 64);
            long p = p0 + wid * 32 + m2 * 16 + hi * 4 + reg;
            if (lo == 0 && p < P) outp[p] = s + pb2v;
        }
}

// ---------------- launch ----------------

extern "C" void kernel_launch(void* const* d_in, const int* in_sizes, int n_in,
                              void* d_out, int out_size, void* d_ws, size_t ws_size,
                              hipStream_t stream) {
    const int*   edge_index = (const int*)d_in[0];
    const int*   edge_type  = (const int*)d_in[1];
    const int*   drug       = (const int*)d_in[2];
    const int*   dis        = (const int*)d_in[3];
    const float* emb        = (const float*)d_in[4];
    const float* rw1        = (const float*)d_in[5];
    const float* sl1        = (const float*)d_in[6];
    const float* b1         = (const float*)d_in[7];
    const float* rw2        = (const float*)d_in[8];
    const float* sl2        = (const float*)d_in[9];
    const float* b2         = (const float*)d_in[10];
    const float* pw1        = (const float*)d_in[11];
    const float* pb1        = (const float*)d_in[12];
    const float* pw2        = (const float*)d_in[13];
    const float* pb2        = (const float*)d_in[14];

    const int E = in_sizes[1];
    const int P = in_sizes[2];
    const int N = in_sizes[4] / D;
    const int R = in_sizes[5] / (D * D);

    const int* srcA = edge_index;
    const int* dstA = edge_index + E;

    const int slotN = E + N + 512 * (R + 2);

    char* ws = (char*)d_ws;
    unsigned short* embb = (unsigned short*)ws; ws += (size_t)N * D * 2;   // aliased as x2b
    unsigned short* x1b  = (unsigned short*)ws; ws += (size_t)N * D * 2;
    unsigned short* y    = (unsigned short*)ws; ws += (size_t)slotN * D * 2;
    unsigned short* wAll1 = (unsigned short*)ws; ws += (size_t)(R + 1) * D * D * 2;
    unsigned short* wAll2 = (unsigned short*)ws; ws += (size_t)(R + 1) * D * D * 2;
    unsigned short* pw1T  = (unsigned short*)ws; ws += (size_t)3 * D * D * 2;
    // zero region (single memset): deg | binCur | slotSrc
    int*   deg     = (int*)ws;   ws += (size_t)R * N * 4;
    int*   binCur  = (int*)ws;   ws += (size_t)R * N * 4;
    int*   slotSrc = (int*)ws;   ws += (size_t)slotN * 4;
    size_t zbytes = (size_t)(2 * R * N + slotN) * 4;
    int* degOff  = (int*)ws; ws += (size_t)R * N * 4;
    int* bsum    = (int*)ws; ws += 256 * 4;
    int* boff    = (int*)ws; ws += 256 * 4;
    int* po      = (int*)ws; ws += 256;
    unsigned short* x2b = embb;

    hipMemsetAsync(deg, 0, zbytes, stream);

    // fused prep (emb->bf16, weights bf16 k-minor pre-swizzled)
    long u0 = (long)N * D / 4;
    long uW = (long)(R + 1) * D * D;
    long utot = u0 + 2 * uW + 3 * D * D;
    k_prep<<<(int)((utot + 255) / 256), 256, 0, stream>>>(emb, rw1, sl1, rw2, sl2, pw1,
                                                          embb, wAll1, wAll2, pw1T, N, R);

    k_count2<<<(E + 255) / 256, 256, 0, stream>>>(edge_type, dstA, E, N, deg);

    // exclusive scan of deg over R*N -> degOff
    int nbS = (R * N + 4095) / 4096;
    k_scan_blk<16><<<nbS, 256, 0, stream>>>(deg, degOff, bsum, R * N);
    k_scan2<<<1, 256, 0, stream>>>(bsum, boff, nbS);
    k_scan3<<<(R * N + 255) / 256, 256, 0, stream>>>(degOff, boff, degOff, R * N, 12);

    k_offsets<<<1, 1, 0, stream>>>(degOff, po, R, N, E);

    // fill slotSrc in (relation,dst)-sorted order (+ self rows)
    k_scatter3<<<(E + N + 255) / 256, 256, 0, stream>>>(edge_type, srcA, dstA, E, N, R,
                                                        degOff, po, binCur, slotSrc);

    int gridM = (E + 511) / 512 + (N + 511) / 512 + R + 2;
    int gridR = (N + 63) / 64;

    // layer 1
    k_gemm_msg<<<gridM, 256, 0, stream>>>(embb, wAll1, slotSrc, po, R, y);
    k_reduce2<true><<<gridR, 256, 0, stream>>>(y, degOff, po, b1, x1b, N, R, E);
    // layer 2
    k_gemm_msg<<<gridM, 256, 0, stream>>>(x1b, wAll2, slotSrc, po, R, y);
    k_reduce2<false><<<gridR, 256, 0, stream>>>(y, degOff, po, b2, x2b, N, R, E);
    // scoring
    k_score<<<(P + 127) / 128, 256, 0, stream>>>(x2b, drug, dis, pw1T, pb1, pw2, pb2,
                                                 (float*)d_out, P);
}